// Round 6
// baseline (63.159 us; speedup 1.0000x reference)
//
#include <hip/hip_runtime.h>
#include <cstdint>
#include <cmath>

#define NN   4096
#define DXX  128
#define DD   64
#define KK   256
#define HH   256
#define DIN  192   // DD + DXX
#define ROWS 16
#define NT   512
#define GRID (NN/ROWS)   // 256 blocks, 1 per CU

// ---------------- Threefry-2x32 (20 rounds), exact JAX semantics ----------------
__device__ __forceinline__ uint32_t rotl32(uint32_t v, uint32_t r){ return (v<<r)|(v>>(32u-r)); }

__device__ __forceinline__ void tf2x32(uint32_t k0, uint32_t k1,
                                       uint32_t x0, uint32_t x1,
                                       uint32_t& o0, uint32_t& o1){
  const uint32_t ks0=k0, ks1=k1, ks2 = k0 ^ k1 ^ 0x1BD11BDAu;
  x0 += ks0; x1 += ks1;
  x0+=x1; x1=rotl32(x1,13); x1^=x0;
  x0+=x1; x1=rotl32(x1,15); x1^=x0;
  x0+=x1; x1=rotl32(x1,26); x1^=x0;
  x0+=x1; x1=rotl32(x1, 6); x1^=x0;
  x0+=ks1; x1+=ks2+1u;
  x0+=x1; x1=rotl32(x1,17); x1^=x0;
  x0+=x1; x1=rotl32(x1,29); x1^=x0;
  x0+=x1; x1=rotl32(x1,16); x1^=x0;
  x0+=x1; x1=rotl32(x1,24); x1^=x0;
  x0+=ks2; x1+=ks0+2u;
  x0+=x1; x1=rotl32(x1,13); x1^=x0;
  x0+=x1; x1=rotl32(x1,15); x1^=x0;
  x0+=x1; x1=rotl32(x1,26); x1^=x0;
  x0+=x1; x1=rotl32(x1, 6); x1^=x0;
  x0+=ks0; x1+=ks1+3u;
  x0+=x1; x1=rotl32(x1,17); x1^=x0;
  x0+=x1; x1=rotl32(x1,29); x1^=x0;
  x0+=x1; x1=rotl32(x1,16); x1^=x0;
  x0+=x1; x1=rotl32(x1,24); x1^=x0;
  x0+=ks1; x1+=ks2+4u;
  x0+=x1; x1=rotl32(x1,13); x1^=x0;
  x0+=x1; x1=rotl32(x1,15); x1^=x0;
  x0+=x1; x1=rotl32(x1,26); x1^=x0;
  x0+=x1; x1=rotl32(x1, 6); x1^=x0;
  x0+=ks2; x1+=ks0+5u;
  o0=x0; o1=x1;
}

__device__ __forceinline__ float gumbel_of(uint32_t ka0, uint32_t ka1, uint32_t idx){
  uint32_t o0,o1; tf2x32(ka0,ka1,0u,idx,o0,o1);
  const uint32_t bits = o0 ^ o1;
  const float TINY = 1.17549435e-38f;
  const float f = __uint_as_float((bits>>9) | 0x3F800000u) - 1.0f;
  const float u = fmaxf(TINY, f + TINY);
  return -logf(-logf(u));
}

// LDS layout (bytes):
//  [0,12288)      in_s[16][192]              } overlaid after MLP by stg[64][65] (16640 B)
//  [12288,28672)  h1  [16][256]              }
//  [28672,45056)  h2  [16][256]
//  [45056,49152)  sgt [16][64]
//  [49152,81920)  wbuf[2][16][256] (weight tiles)  -> overlaid by sp[2][16][256]
#define OFF_H1   12288
#define OFF_H2   28672
#define OFF_SGT  45056
#define OFF_WB   49152

__global__ __launch_bounds__(NT,2) void k_fused(
    const float* __restrict__ z, const float* __restrict__ ks,
    const float* __restrict__ xt, const void* __restrict__ maskp,
    const float* __restrict__ tr, const float* __restrict__ spk,
    const float* __restrict__ W1, const float* __restrict__ b1,
    const float* __restrict__ W2, const float* __restrict__ b2,
    const float* __restrict__ W3, const float* __restrict__ b3,
    const float* __restrict__ Cg, const int* __restrict__ seedp,
    float* __restrict__ out_z, float* __restrict__ out_kl,
    float* __restrict__ out_dkl, float* __restrict__ out_qk)
{
  const int t    = threadIdx.x;
  const int lane = t & 63;
  const int wv   = t >> 6;          // wave 0..7
  const int col  = t & 255;         // MLP1/2 output column
  const int rh   = t >> 8;          // half (0/1): rows rh*8..rh*8+7 / distance d-half
  const int n0   = blockIdx.x * ROWS;
  const int nA   = n0 + wv;         // finalize: wave wv owns rows nA and nB
  const int nB   = n0 + 8 + wv;

  __shared__ __align__(16) char smem[81920];
  float (*in_s)[DIN] = (float(*)[DIN]) smem;
  float (*h1 )[HH]   = (float(*)[HH]) (smem + OFF_H1);
  float (*h2 )[HH]   = (float(*)[HH]) (smem + OFF_H2);
  float (*sgt)[DD]   = (float(*)[DD]) (smem + OFF_SGT);
  float *wbase       = (float*)       (smem + OFF_WB);   // wbuf / sp overlay
  float (*stg)[65]   = (float(*)[65]) smem;              // codebook chunk overlay
  __shared__ int sh_flag;

  // ---- early long-latency loads: ks rows -> kidx -> transition rows; mask raw ----
  auto kidx_of=[&](const float4& kq)->int{
    int kv=0x7fffffff;
    if (isfinite(kq.x)&&kq.x>0.5f) kv=4*lane+0;
    if (isfinite(kq.y)&&kq.y>0.5f&&4*lane+1<kv) kv=4*lane+1;
    if (isfinite(kq.z)&&kq.z>0.5f&&4*lane+2<kv) kv=4*lane+2;
    if (isfinite(kq.w)&&kq.w>0.5f&&4*lane+3<kv) kv=4*lane+3;
    unsigned long long bl=__ballot(kv!=0x7fffffff);
    if (bl){ int src=(int)__builtin_ctzll(bl); kv=__shfl(kv,src,64); } else kv=0;
    return kv;
  };
  const float4 ksA = ((const float4*)ks)[(size_t)nA*(KK/4)+lane];
  const float4 ksB = ((const float4*)ks)[(size_t)nB*(KK/4)+lane];
  const int kA = kidx_of(ksA), kB = kidx_of(ksB);
  const float4 trA = ((const float4*)tr)[(size_t)nA*(KK*KK/4)+(size_t)kA*(KK/4)+lane];
  const float4 trB = ((const float4*)tr)[(size_t)nB*(KK*KK/4)+(size_t)kB*(KK/4)+lane];
  const unsigned char mbA = ((const unsigned char*)maskp)[nA];
  const unsigned char mbB = ((const unsigned char*)maskp)[nB];
  const uint32_t      mwA = ((const uint32_t*)maskp)[nA];
  const uint32_t      mwB = ((const uint32_t*)maskp)[nB];

  // ---- mask dtype autodetect ----
  if (t==0) sh_flag = 0;
  __syncthreads();
  {
    const uint32_t* mw = (const uint32_t*)maskp;
    uint32_t bad=0;
    #pragma unroll
    for (int q=0;q<2;++q){ uint32_t wd=mw[t+q*NT]; if (wd!=0u && wd!=1u && wd!=0x3F800000u) bad=1; }
    if (bad) atomicOr(&sh_flag,1);
  }

  // ---- weight tile staging helpers (coalesced float4, line-spread) ----
  auto stageW = [&](const float* __restrict__ W, int dd0, int p){   // 16 x 256 tile
    #pragma unroll
    for (int q=0;q<2;++q){
      int f = q*NT + t;                 // 0..1023 float4 slots
      int dd = f>>6, c4 = f&63;
      float4 v = *(const float4*)&W[(size_t)(dd0+dd)*HH + c4*4];
      *(float4*)&wbase[p*4096 + dd*256 + c4*4] = v;
    }
  };
  auto stageW3 = [&](int dd0, int p){                               // 32 x 64 tile
    int dd = t>>4, c4 = t&15;
    float4 v = *(const float4*)&W3[(size_t)(dd0+dd)*DD + c4*4];
    *(float4*)&wbase[p*4096 + dd*64 + c4*4] = v;
  };

  // ---- MLP input staging + W1 tile 0 ----
  for (int i=t; i<ROWS*DIN; i+=NT){
    int r=i/DIN, d=i%DIN; int n=n0+r; float v;
    if (d<DD){ v = z[(size_t)n*DD+d]; if(!isfinite(v)) v=0.f; }
    else     { v = xt[(size_t)n*DXX + (d-DD)]; }
    in_s[r][d] = v;
  }
  stageW(W1, 0, 0);
  __syncthreads();
  const int flag = sh_flag;

  float acc[8];
  // ================= MLP1: tanh([z,x]@W1+b1), 12 LDS-staged K-tiles ==========
  {
    const float bb = b1[col];
    #pragma unroll
    for (int j=0;j<8;++j) acc[j]=bb;
    int p=0;
    for (int T=0; T<12; ++T){
      if (T<11) stageW(W1, (T+1)*16, p^1);
      const int dd0 = T*16;
      #pragma unroll
      for (int d4=0; d4<16; d4+=4){
        float w0=wbase[p*4096+(d4+0)*256+col];
        float w1=wbase[p*4096+(d4+1)*256+col];
        float w2=wbase[p*4096+(d4+2)*256+col];
        float w3=wbase[p*4096+(d4+3)*256+col];
        #pragma unroll
        for (int j=0;j<8;++j){
          float4 x = *(const float4*)&in_s[rh*8+j][dd0+d4];
          acc[j]+=x.x*w0; acc[j]+=x.y*w1; acc[j]+=x.z*w2; acc[j]+=x.w*w3;
        }
      }
      __syncthreads();
      p^=1;
    }
    #pragma unroll
    for (int j=0;j<8;++j) h1[rh*8+j][col] = tanhf(acc[j]);
  }
  stageW(W2, 0, 0);
  __syncthreads();
  // ================= MLP2: tanh(h1@W2+b2), 16 K-tiles ========================
  {
    const float bb = b2[col];
    #pragma unroll
    for (int j=0;j<8;++j) acc[j]=bb;
    int p=0;
    for (int T=0; T<16; ++T){
      if (T<15) stageW(W2, (T+1)*16, p^1);
      const int dd0 = T*16;
      #pragma unroll
      for (int d4=0; d4<16; d4+=4){
        float w0=wbase[p*4096+(d4+0)*256+col];
        float w1=wbase[p*4096+(d4+1)*256+col];
        float w2=wbase[p*4096+(d4+2)*256+col];
        float w3=wbase[p*4096+(d4+3)*256+col];
        #pragma unroll
        for (int j=0;j<8;++j){
          float4 x = *(const float4*)&h1[rh*8+j][dd0+d4];
          acc[j]+=x.x*w0; acc[j]+=x.y*w1; acc[j]+=x.z*w2; acc[j]+=x.w*w3;
        }
      }
      __syncthreads();
      p^=1;
    }
    #pragma unroll
    for (int j=0;j<8;++j) h2[rh*8+j][col] = tanhf(acc[j]);
  }
  stageW3(0, 0);
  __syncthreads();
  // ================= MLP3: gt = h2@W3+b3, 8 K-tiles of 32 ====================
  {
    const int c3 = t&63, rg = t>>6;     // rows 2rg, 2rg+1
    float a0=b3[c3], a1=b3[c3];
    int p=0;
    for (int T=0; T<8; ++T){
      if (T<7) stageW3((T+1)*32, p^1);
      const int dd0 = T*32;
      #pragma unroll
      for (int d4=0; d4<32; d4+=4){
        float w0=wbase[p*4096+(d4+0)*64+c3];
        float w1=wbase[p*4096+(d4+1)*64+c3];
        float w2=wbase[p*4096+(d4+2)*64+c3];
        float w3=wbase[p*4096+(d4+3)*64+c3];
        float4 xa=*(const float4*)&h2[2*rg  ][dd0+d4];
        float4 xb=*(const float4*)&h2[2*rg+1][dd0+d4];
        a0+=xa.x*w0; a0+=xa.y*w1; a0+=xa.z*w2; a0+=xa.w*w3;
        a1+=xb.x*w0; a1+=xb.y*w1; a1+=xb.z*w2; a1+=xb.w*w3;
      }
      __syncthreads();
      p^=1;
    }
    sgt[2*rg][c3]=a0; sgt[2*rg+1][c3]=a1;
  }

  // ---- gumbel precompute (pure VALU; mask known) ----
  uint32_t ka0,ka1;
  tf2x32(0u,(uint32_t)seedp[0],0u,0u,ka0,ka1);   // partitionable split: k_rng
  const bool mA = flag ? (mbA!=0) : (mwA!=0u);
  const bool mB = flag ? (mbB!=0) : (mwB!=0u);
  float gA0=0,gA1=0,gA2=0,gA3=0,gB0=0,gB1=0,gB2=0,gB3=0;
  if (!mA){
    gA0=gumbel_of(ka0,ka1,(uint32_t)(nA*KK+4*lane+0));
    gA1=gumbel_of(ka0,ka1,(uint32_t)(nA*KK+4*lane+1));
    gA2=gumbel_of(ka0,ka1,(uint32_t)(nA*KK+4*lane+2));
    gA3=gumbel_of(ka0,ka1,(uint32_t)(nA*KK+4*lane+3));
  }
  if (!mB){
    gB0=gumbel_of(ka0,ka1,(uint32_t)(nB*KK+4*lane+0));
    gB1=gumbel_of(ka0,ka1,(uint32_t)(nB*KK+4*lane+1));
    gB2=gumbel_of(ka0,ka1,(uint32_t)(nB*KK+4*lane+2));
    gB3=gumbel_of(ka0,ka1,(uint32_t)(nB*KK+4*lane+3));
  }

  // ---- codebook -> registers: thread (col,rh) holds C[col][rh*32..+31] ----
  float creg[32];
  #pragma unroll 1
  for (int cc=0; cc<4; ++cc){
    __syncthreads();                 // protect stg region reuse (sgt published on cc=0)
    #pragma unroll
    for (int q=0;q<2;++q){
      int f=q*NT+t;
      float4 v=((const float4*)Cg)[cc*1024+f];
      int cl=f>>4, d0=(f&15)*4;
      stg[cl][d0+0]=v.x; stg[cl][d0+1]=v.y; stg[cl][d0+2]=v.z; stg[cl][d0+3]=v.w;
    }
    __syncthreads();
    if ((col>>6)==cc){
      #pragma unroll
      for (int j=0;j<32;++j) creg[j]=stg[col&63][rh*32+j];
    }
  }
  __syncthreads();

  // ---- distance partials (half-split, same order as round 5) into sp ----
  float* sp = wbase;                 // sp[h][r][c] = wbase[h*4096 + r*256 + c]
  #pragma unroll 1
  for (int r=0;r<ROWS;++r){
    float p=0.f;
    #pragma unroll
    for (int d4=0; d4<32; d4+=4){
      float4 s4 = *(const float4*)&sgt[r][rh*32+d4];
      float df;
      df=s4.x-creg[d4+0]; p+=df*df;
      df=s4.y-creg[d4+1]; p+=df*df;
      df=s4.z-creg[d4+2]; p+=df*df;
      df=s4.w-creg[d4+3]; p+=df*df;
    }
    sp[rh*4096 + r*256 + col] = p;
  }
  __syncthreads();

  // ---- wave-local finalize: wave wv owns rows nA (r=wv) and nB (r=wv+8) ----
  auto process=[&](int n,int r,const float4& ksq,const float4& trq,bool m,
                   float g0,float g1,float g2,float g3){
    // VQ argmin (first-index tie-break)
    float4 p0 = *(const float4*)&sp[       r*256 + 4*lane];
    float4 p1 = *(const float4*)&sp[4096 + r*256 + 4*lane];
    float dv = sqrtf(p0.x+p1.x); int di = 4*lane;
    { float d1=sqrtf(p0.y+p1.y); if(d1<dv){dv=d1;di=4*lane+1;}
      float d2=sqrtf(p0.z+p1.z); if(d2<dv){dv=d2;di=4*lane+2;}
      float d3=sqrtf(p0.w+p1.w); if(d3<dv){dv=d3;di=4*lane+3;} }
    #pragma unroll
    for (int mm=32;mm;mm>>=1){
      float ov=__shfl_xor(dv,mm,64); int oi=__shfl_xor(di,mm,64);
      if (ov<dv||(ov==dv&&oi<di)){dv=ov;di=oi;}
    }
    const int qk=di;

    // prior normalization
    float s=((trq.x+trq.y)+trq.z)+trq.w;
    #pragma unroll
    for (int mm=32;mm;mm>>=1) s+=__shfl_xor(s,mm,64);
    float q0=trq.x/s, q1=trq.y/s, q2=trq.z/s, q3=trq.w/s;
    { bool f0=isfinite(ksq.x),f1=isfinite(ksq.y),f2=isfinite(ksq.z),f3=isfinite(ksq.w);
      if (__any(!(f0&&f1&&f2&&f3))){
        float4 sq=((const float4*)spk)[(size_t)n*(KK/4)+lane];
        if(!f0)q0=sq.x; if(!f1)q1=sq.y; if(!f2)q2=sq.z; if(!f3)q3=sq.w;
      } }
    const float lp0=logf(q0), lp1=logf(q1), lp2=logf(q2), lp3=logf(q3);
    const int jq=qk&3;
    float lps=(jq==0)?lp0:((jq==1)?lp1:((jq==2)?lp2:lp3));
    const float logqk=__shfl(lps,qk>>2,64);

    int sel;
    if (m){ sel=qk; }
    else {
      float sc=g0+lp0; int si=4*lane;
      { float g=g1+lp1; if(g>sc){sc=g;si=4*lane+1;} }
      { float g=g2+lp2; if(g>sc){sc=g;si=4*lane+2;} }
      { float g=g3+lp3; if(g>sc){sc=g;si=4*lane+3;} }
      #pragma unroll
      for (int mm=32;mm;mm>>=1){
        float ov=__shfl_xor(sc,mm,64); int oi=__shfl_xor(si,mm,64);
        if (ov>sc||(ov==sc&&oi<si)){sc=ov;si=oi;}
      }
      sel=si;
    }

    ((float4*)out_qk)[(size_t)n*(KK/4)+lane]=make_float4(
      (4*lane+0==qk)?1.f:0.f,(4*lane+1==qk)?1.f:0.f,
      (4*lane+2==qk)?1.f:0.f,(4*lane+3==qk)?1.f:0.f);

    const float c=Cg[(size_t)sel*DD+lane];
    out_z[(size_t)n*DD+lane]=c;
    float df=sgt[r][lane]-c;
    float p=df*df;
    #pragma unroll
    for (int mm=32;mm;mm>>=1) p+=__shfl_xor(p,mm,64);
    if (lane==0){
      float tt=sqrtf(p);
      float dkl=-logqk;
      out_kl[n]=(tt+0.25f*tt)+dkl;
      out_dkl[n]=dkl;
    }
  };
  process(nA, wv,   ksA, trA, mA, gA0,gA1,gA2,gA3);
  process(nB, wv+8, ksB, trB, mB, gB0,gB1,gB2,gB3);
}

extern "C" void kernel_launch(void* const* d_in, const int* in_sizes, int n_in,
                              void* d_out, int out_size, void* d_ws, size_t ws_size,
                              hipStream_t stream){
  const float* z    = (const float*)d_in[1];
  const float* ksm  = (const float*)d_in[2];
  const float* xt   = (const float*)d_in[3];
  const void*  mask = d_in[4];
  const float* tr   = (const float*)d_in[5];
  const float* spk  = (const float*)d_in[6];
  const float* W1   = (const float*)d_in[7];
  const float* b1   = (const float*)d_in[8];
  const float* W2   = (const float*)d_in[9];
  const float* b2   = (const float*)d_in[10];
  const float* W3   = (const float*)d_in[11];
  const float* b3   = (const float*)d_in[12];
  const float* C    = (const float*)d_in[13];
  const int*   seed = (const int*)d_in[14];

  float* out_z   = (float*)d_out;                // N*D
  float* out_kl  = out_z   + (size_t)NN*DD;      // N
  float* out_dkl = out_kl  + NN;                 // N
  float* out_qk  = out_dkl + NN;                 // N*K

  k_fused<<<GRID,NT,0,stream>>>(z, ksm, xt, mask, tr, spk,
                                W1, b1, W2, b2, W3, b3, C, seed,
                                out_z, out_kl, out_dkl, out_qk);
}

// Round 7
// 59.014 us; speedup vs baseline: 1.0702x; 1.0702x over previous
//
#include <hip/hip_runtime.h>
#include <cstdint>
#include <cmath>

#define NN   4096
#define DXX  128
#define DD   64
#define KK   256
#define HH   256
#define DIN  192   // DD + DXX
#define RB   4      // rows per block
#define NT   256
#define GRID (NN/RB)   // 1024 blocks, 4 per CU -> 4 waves/SIMD

// ---------------- Threefry-2x32 (20 rounds), exact JAX semantics ----------------
__device__ __forceinline__ uint32_t rotl32(uint32_t v, uint32_t r){ return (v<<r)|(v>>(32u-r)); }

__device__ __forceinline__ void tf2x32(uint32_t k0, uint32_t k1,
                                       uint32_t x0, uint32_t x1,
                                       uint32_t& o0, uint32_t& o1){
  const uint32_t ks0=k0, ks1=k1, ks2 = k0 ^ k1 ^ 0x1BD11BDAu;
  x0 += ks0; x1 += ks1;
  x0+=x1; x1=rotl32(x1,13); x1^=x0;
  x0+=x1; x1=rotl32(x1,15); x1^=x0;
  x0+=x1; x1=rotl32(x1,26); x1^=x0;
  x0+=x1; x1=rotl32(x1, 6); x1^=x0;
  x0+=ks1; x1+=ks2+1u;
  x0+=x1; x1=rotl32(x1,17); x1^=x0;
  x0+=x1; x1=rotl32(x1,29); x1^=x0;
  x0+=x1; x1=rotl32(x1,16); x1^=x0;
  x0+=x1; x1=rotl32(x1,24); x1^=x0;
  x0+=ks2; x1+=ks0+2u;
  x0+=x1; x1=rotl32(x1,13); x1^=x0;
  x0+=x1; x1=rotl32(x1,15); x1^=x0;
  x0+=x1; x1=rotl32(x1,26); x1^=x0;
  x0+=x1; x1=rotl32(x1, 6); x1^=x0;
  x0+=ks0; x1+=ks1+3u;
  x0+=x1; x1=rotl32(x1,17); x1^=x0;
  x0+=x1; x1=rotl32(x1,29); x1^=x0;
  x0+=x1; x1=rotl32(x1,16); x1^=x0;
  x0+=x1; x1=rotl32(x1,24); x1^=x0;
  x0+=ks1; x1+=ks2+4u;
  x0+=x1; x1=rotl32(x1,13); x1^=x0;
  x0+=x1; x1=rotl32(x1,15); x1^=x0;
  x0+=x1; x1=rotl32(x1,26); x1^=x0;
  x0+=x1; x1=rotl32(x1, 6); x1^=x0;
  x0+=ks2; x1+=ks0+5u;
  o0=x0; o1=x1;
}

__device__ __forceinline__ float gumbel_of(uint32_t ka0, uint32_t ka1, uint32_t idx){
  uint32_t o0,o1; tf2x32(ka0,ka1,0u,idx,o0,o1);
  const uint32_t bits = o0 ^ o1;
  const float TINY = 1.17549435e-38f;
  const float f = __uint_as_float((bits>>9) | 0x3F800000u) - 1.0f;
  const float u = fmaxf(TINY, f + TINY);
  return -logf(-logf(u));
}

// LDS layout (bytes):
//  [0,3072)       in_s[4][192]
//  [3072,7168)    h1[4][256]
//  [7168,11264)   h2[4][256]
//  [11264,12288)  sgt[4][64]
//  [12288,28672)  sp (16 KB): MLP1/2 partials [4][4][256]; MLP3 partials [8][4][64] (8 KB)
//  [12288,28928)  stg[64][65] overlay (codebook transpose; after MLP3 combine)
//  [24576,28672)  sdist[4][256] overlay (after stg reads complete)
#define OFF_H1   3072
#define OFF_H2   7168
#define OFF_SGT  11264
#define OFF_SP   12288
#define OFF_SD   24576
#define SMEM_SZ  28928

__global__ __launch_bounds__(NT,4) void k_fused(
    const float* __restrict__ z, const float* __restrict__ ks,
    const float* __restrict__ xt, const void* __restrict__ maskp,
    const float* __restrict__ tr, const float* __restrict__ spk,
    const float* __restrict__ W1, const float* __restrict__ b1,
    const float* __restrict__ W2, const float* __restrict__ b2,
    const float* __restrict__ W3, const float* __restrict__ b3,
    const float* __restrict__ Cg, const int* __restrict__ seedp,
    float* __restrict__ out_z, float* __restrict__ out_kl,
    float* __restrict__ out_dkl, float* __restrict__ out_qk)
{
  const int t    = threadIdx.x;
  const int lane = t & 63;
  const int wv   = t >> 6;          // wave 0..3
  const int n0   = blockIdx.x * RB;
  const int nw   = n0 + wv;         // finalize: wave wv owns row nw

  __shared__ __align__(16) char smem[SMEM_SZ];
  float (*in_s)[DIN] = (float(*)[DIN]) smem;
  float (*h1 )[HH]   = (float(*)[HH]) (smem + OFF_H1);
  float (*h2 )[HH]   = (float(*)[HH]) (smem + OFF_H2);
  float (*sgt)[DD]   = (float(*)[DD]) (smem + OFF_SGT);
  float *sp          = (float*)       (smem + OFF_SP);
  float (*stg)[65]   = (float(*)[65]) (smem + OFF_SP);
  float *sdist       = (float*)       (smem + OFF_SD);
  __shared__ int sh_flag;

  // ---- early load: this wave's k_sample row (latency hidden under MLP) ----
  const float4 ksq = ((const float4*)ks)[(size_t)nw*(KK/4) + lane];

  // ---- mask dtype autodetect ----
  if (t==0) sh_flag = 0;
  __syncthreads();
  {
    const uint32_t* mw = (const uint32_t*)maskp;
    uint32_t bad=0;
    #pragma unroll
    for (int q=0;q<4;++q){ uint32_t wd=mw[t+q*NT]; if (wd!=0u && wd!=1u && wd!=0x3F800000u) bad=1; }
    if (bad) atomicOr(&sh_flag,1);
  }

  // ---- MLP input staging ----
  for (int i=t; i<RB*DIN; i+=NT){
    int r=i/DIN, d=i%DIN; int n=n0+r; float v;
    if (d<DD){ v = z[(size_t)n*DD+d]; if(!isfinite(v)) v=0.f; }
    else     { v = xt[(size_t)n*DXX + (d-DD)]; }
    in_s[r][d] = v;
  }
  __syncthreads();
  const int flag = sh_flag;

  const int c  = lane;   // col base: cols c, c+64, c+128, c+192
  const int kq = wv;     // K-quarter (wave-uniform)

  // ================= MLP1: [z,x]@W1 partials (C=4 cols/thread) =================
  {
    float acc[RB][4] = {};
    const int kbase = kq*48;
    #pragma unroll 2
    for (int s=0; s<12; ++s){
      const int k0 = kbase + s*4;
      float w[4][4];
      #pragma unroll
      for (int i=0;i<4;++i)
        #pragma unroll
        for (int j=0;j<4;++j) w[i][j] = W1[(size_t)(k0+i)*HH + c + 64*j];
      #pragma unroll
      for (int r=0;r<RB;++r){
        float4 x = *(const float4*)&in_s[r][k0];
        #pragma unroll
        for (int j=0;j<4;++j){
          acc[r][j]+=x.x*w[0][j]; acc[r][j]+=x.y*w[1][j];
          acc[r][j]+=x.z*w[2][j]; acc[r][j]+=x.w*w[3][j];
        }
      }
    }
    #pragma unroll
    for (int r=0;r<RB;++r)
      #pragma unroll
      for (int j=0;j<4;++j) sp[kq*1024 + r*256 + c + 64*j] = acc[r][j];
  }
  __syncthreads();
  { // combine + bias + tanh -> h1
    const int rs = t>>6, c4 = t&63;
    float4 p0 = *(const float4*)&sp[0*1024 + rs*256 + 4*c4];
    float4 p1 = *(const float4*)&sp[1*1024 + rs*256 + 4*c4];
    float4 p2 = *(const float4*)&sp[2*1024 + rs*256 + 4*c4];
    float4 p3 = *(const float4*)&sp[3*1024 + rs*256 + 4*c4];
    float4 b  = *(const float4*)&b1[4*c4];
    float4 h;
    h.x = tanhf((((b.x+p0.x)+p1.x)+p2.x)+p3.x);
    h.y = tanhf((((b.y+p0.y)+p1.y)+p2.y)+p3.y);
    h.z = tanhf((((b.z+p0.z)+p1.z)+p2.z)+p3.z);
    h.w = tanhf((((b.w+p0.w)+p1.w)+p2.w)+p3.w);
    *(float4*)&h1[rs][4*c4] = h;
  }
  __syncthreads();

  // ================= MLP2: h1@W2 partials =================
  {
    float acc[RB][4] = {};
    const int kbase = kq*64;
    #pragma unroll 2
    for (int s=0; s<16; ++s){
      const int k0 = kbase + s*4;
      float w[4][4];
      #pragma unroll
      for (int i=0;i<4;++i)
        #pragma unroll
        for (int j=0;j<4;++j) w[i][j] = W2[(size_t)(k0+i)*HH + c + 64*j];
      #pragma unroll
      for (int r=0;r<RB;++r){
        float4 x = *(const float4*)&h1[r][k0];
        #pragma unroll
        for (int j=0;j<4;++j){
          acc[r][j]+=x.x*w[0][j]; acc[r][j]+=x.y*w[1][j];
          acc[r][j]+=x.z*w[2][j]; acc[r][j]+=x.w*w[3][j];
        }
      }
    }
    #pragma unroll
    for (int r=0;r<RB;++r)
      #pragma unroll
      for (int j=0;j<4;++j) sp[kq*1024 + r*256 + c + 64*j] = acc[r][j];
  }
  __syncthreads();
  { // combine + bias + tanh -> h2
    const int rs = t>>6, c4 = t&63;
    float4 p0 = *(const float4*)&sp[0*1024 + rs*256 + 4*c4];
    float4 p1 = *(const float4*)&sp[1*1024 + rs*256 + 4*c4];
    float4 p2 = *(const float4*)&sp[2*1024 + rs*256 + 4*c4];
    float4 p3 = *(const float4*)&sp[3*1024 + rs*256 + 4*c4];
    float4 b  = *(const float4*)&b2[4*c4];
    float4 h;
    h.x = tanhf((((b.x+p0.x)+p1.x)+p2.x)+p3.x);
    h.y = tanhf((((b.y+p0.y)+p1.y)+p2.y)+p3.y);
    h.z = tanhf((((b.z+p0.z)+p1.z)+p2.z)+p3.z);
    h.w = tanhf((((b.w+p0.w)+p1.w)+p2.w)+p3.w);
    *(float4*)&h2[rs][4*c4] = h;
  }
  __syncthreads();

  // ================= MLP3: h2@W3 partials (8-way K-split, 2 cols/thread) ======
  {
    const int c3 = t & 31, kq3 = t >> 5;   // kq3 0..7
    float acc3[RB][2] = {};
    #pragma unroll 2
    for (int s=0; s<8; ++s){
      const int k0 = kq3*32 + s*4;
      float w[4][2];
      #pragma unroll
      for (int i=0;i<4;++i){
        w[i][0] = W3[(size_t)(k0+i)*DD + c3];
        w[i][1] = W3[(size_t)(k0+i)*DD + c3 + 32];
      }
      #pragma unroll
      for (int r=0;r<RB;++r){
        float4 x = *(const float4*)&h2[r][k0];
        #pragma unroll
        for (int j=0;j<2;++j){
          acc3[r][j]+=x.x*w[0][j]; acc3[r][j]+=x.y*w[1][j];
          acc3[r][j]+=x.z*w[2][j]; acc3[r][j]+=x.w*w[3][j];
        }
      }
    }
    #pragma unroll
    for (int r=0;r<RB;++r){
      sp[kq3*256 + r*64 + c3     ] = acc3[r][0];
      sp[kq3*256 + r*64 + c3 + 32] = acc3[r][1];
    }
  }
  __syncthreads();
  if (t < 64){ // combine -> sgt
    const int rs = t>>4, c4 = t&15;
    float4 a = *(const float4*)&b3[4*c4];
    #pragma unroll
    for (int q=0;q<8;++q){
      float4 p = *(const float4*)&sp[q*256 + rs*64 + 4*c4];
      a.x+=p.x; a.y+=p.y; a.z+=p.z; a.w+=p.w;
    }
    *(float4*)&sgt[rs][4*c4] = a;
  }
  __syncthreads();

  // ---- carry index + transition row issued early (hidden under codebook/dist) ----
  int kv=0x7fffffff;
  if (isfinite(ksq.x)&&ksq.x>0.5f) kv=4*lane+0;
  if (isfinite(ksq.y)&&ksq.y>0.5f&&4*lane+1<kv) kv=4*lane+1;
  if (isfinite(ksq.z)&&ksq.z>0.5f&&4*lane+2<kv) kv=4*lane+2;
  if (isfinite(ksq.w)&&ksq.w>0.5f&&4*lane+3<kv) kv=4*lane+3;
  { unsigned long long bl=__ballot(kv!=0x7fffffff);
    if (bl){ int src=(int)__builtin_ctzll(bl); kv=__shfl(kv,src,64); } else kv=0; }
  const int kidx = kv;
  const float4 trq = ((const float4*)tr)[(size_t)nw*(KK*KK/4)+(size_t)kidx*(KK/4)+lane];

  // ---- codebook -> registers: thread t owns code t (LDS transpose, 4 chunks) ----
  float creg[DD];
  #pragma unroll 1
  for (int cc=0; cc<4; ++cc){
    __syncthreads();
    #pragma unroll
    for (int q=0;q<4;++q){
      int f=q*NT+t;
      float4 v=((const float4*)Cg)[cc*1024+f];
      int cl=f>>4, d0=(f&15)*4;
      stg[cl][d0+0]=v.x; stg[cl][d0+1]=v.y; stg[cl][d0+2]=v.z; stg[cl][d0+3]=v.w;
    }
    __syncthreads();
    if (wv==cc){
      #pragma unroll
      for (int d=0;d<DD;++d) creg[d]=stg[lane][d];
    }
  }
  __syncthreads();   // stg reads complete before sdist overlay writes

  // ---- distances: thread t owns code t, sequential d order (as prior rounds) ----
  #pragma unroll 1
  for (int r=0;r<RB;++r){
    float d2=0.f;
    #pragma unroll
    for (int d4=0; d4<DD; d4+=4){
      float4 s4 = *(const float4*)&sgt[r][d4];
      float df;
      df=s4.x-creg[d4+0]; d2+=df*df;
      df=s4.y-creg[d4+1]; d2+=df*df;
      df=s4.z-creg[d4+2]; d2+=df*df;
      df=s4.w-creg[d4+3]; d2+=df*df;
    }
    sdist[r*256 + t] = sqrtf(d2);
  }
  __syncthreads();

  // ---- wave-local finalize: wave wv owns row nw ----
  uint32_t ka0,ka1;
  tf2x32(0u,(uint32_t)seedp[0],0u,0u,ka0,ka1);   // partitionable split: k_rng

  // VQ argmin (first-index tie-break)
  float4 dq = *(const float4*)&sdist[wv*256 + 4*lane];
  float dv=dq.x; int di=4*lane;
  if (dq.y<dv){dv=dq.y;di=4*lane+1;}
  if (dq.z<dv){dv=dq.z;di=4*lane+2;}
  if (dq.w<dv){dv=dq.w;di=4*lane+3;}
  #pragma unroll
  for (int m=32;m;m>>=1){
    float ov=__shfl_xor(dv,m,64); int oi=__shfl_xor(di,m,64);
    if (ov<dv||(ov==dv&&oi<di)){dv=ov;di=oi;}
  }
  const int qk=di;

  // prior normalization
  float s=((trq.x+trq.y)+trq.z)+trq.w;
  #pragma unroll
  for (int m=32;m;m>>=1) s+=__shfl_xor(s,m,64);
  float q0=trq.x/s, q1=trq.y/s, q2=trq.z/s, q3=trq.w/s;
  { bool f0=isfinite(ksq.x),f1=isfinite(ksq.y),f2=isfinite(ksq.z),f3=isfinite(ksq.w);
    if (__any(!(f0&&f1&&f2&&f3))){
      float4 sq=((const float4*)spk)[(size_t)nw*(KK/4)+lane];
      if(!f0)q0=sq.x; if(!f1)q1=sq.y; if(!f2)q2=sq.z; if(!f3)q3=sq.w;
    } }
  const float lp0=logf(q0), lp1=logf(q1), lp2=logf(q2), lp3=logf(q3);
  const int jq=qk&3;
  float lps=(jq==0)?lp0:((jq==1)?lp1:((jq==2)?lp2:lp3));
  const float logqk=__shfl(lps,qk>>2,64);

  // mask (uniform per row)
  bool m;
  if (flag) m=((const unsigned char*)maskp)[nw]!=0;
  else      m=((const uint32_t*)maskp)[nw]!=0u;

  int sel;
  if (m){ sel=qk; }
  else {
    float sc=gumbel_of(ka0,ka1,(uint32_t)(nw*KK+4*lane+0))+lp0; int si=4*lane;
    { float g=gumbel_of(ka0,ka1,(uint32_t)(nw*KK+4*lane+1))+lp1; if(g>sc){sc=g;si=4*lane+1;} }
    { float g=gumbel_of(ka0,ka1,(uint32_t)(nw*KK+4*lane+2))+lp2; if(g>sc){sc=g;si=4*lane+2;} }
    { float g=gumbel_of(ka0,ka1,(uint32_t)(nw*KK+4*lane+3))+lp3; if(g>sc){sc=g;si=4*lane+3;} }
    #pragma unroll
    for (int mm=32;mm;mm>>=1){
      float ov=__shfl_xor(sc,mm,64); int oi=__shfl_xor(si,mm,64);
      if (ov>sc||(ov==sc&&oi<si)){sc=ov;si=oi;}
    }
    sel=si;
  }

  ((float4*)out_qk)[(size_t)nw*(KK/4)+lane]=make_float4(
    (4*lane+0==qk)?1.f:0.f,(4*lane+1==qk)?1.f:0.f,
    (4*lane+2==qk)?1.f:0.f,(4*lane+3==qk)?1.f:0.f);

  const float cc=Cg[(size_t)sel*DD+lane];
  out_z[(size_t)nw*DD+lane]=cc;
  float df=sgt[wv][lane]-cc;
  float p=df*df;
  #pragma unroll
  for (int mm=32;mm;mm>>=1) p+=__shfl_xor(p,mm,64);
  if (lane==0){
    float tt=sqrtf(p);
    float dkl=-logqk;
    out_kl[nw]=(tt+0.25f*tt)+dkl;
    out_dkl[nw]=dkl;
  }
}

extern "C" void kernel_launch(void* const* d_in, const int* in_sizes, int n_in,
                              void* d_out, int out_size, void* d_ws, size_t ws_size,
                              hipStream_t stream){
  const float* z    = (const float*)d_in[1];
  const float* ksm  = (const float*)d_in[2];
  const float* xt   = (const float*)d_in[3];
  const void*  mask = d_in[4];
  const float* tr   = (const float*)d_in[5];
  const float* spk  = (const float*)d_in[6];
  const float* W1   = (const float*)d_in[7];
  const float* b1   = (const float*)d_in[8];
  const float* W2   = (const float*)d_in[9];
  const float* b2   = (const float*)d_in[10];
  const float* W3   = (const float*)d_in[11];
  const float* b3   = (const float*)d_in[12];
  const float* C    = (const float*)d_in[13];
  const int*   seed = (const int*)d_in[14];

  float* out_z   = (float*)d_out;                // N*D
  float* out_kl  = out_z   + (size_t)NN*DD;      // N
  float* out_dkl = out_kl  + NN;                 // N
  float* out_qk  = out_dkl + NN;                 // N*K

  k_fused<<<GRID,NT,0,stream>>>(z, ksm, xt, mask, tr, spk,
                                W1, b1, W2, b2, W3, b3, C, seed,
                                out_z, out_kl, out_dkl, out_qk);
}